// Round 11
// baseline (43.225 us; speedup 1.0000x reference)
//
#include <hip/hip_runtime.h>

#define EPS 1e-8f

__device__ __forceinline__ float sigmoidf_(float x) {
    return 1.0f / (1.0f + expf(-x));
}

// ---------------------------------------------------------------------------
// Two-kernel chunked scan (R4 structure) + forced deep load prefetch in BOTH
// kernels. Chains (b,f) as bf in [0,BF); time in C chunks of L=50.
// Thread (bf,c) owns chunk c of chain bf; consecutive threads = consecutive
// bf -> wave-coalesced 256 B per load instruction.
//
// The compiler sinks loads to point-of-use when the consumer is a serial
// recurrence (seen as VGPR=24-28, ~2 loads in flight, 2.4 TB/s in R7/R8).
// Fix: load all L elements into a register array, then an asm memory
// clobber pins every load before the first use -> ~L loads in flight/wave.
// ---------------------------------------------------------------------------

template <int L>
__global__ __launch_bounds__(256)
void fns11_aggregate(const float* __restrict__ mag,
                     const float* __restrict__ alpha,
                     float* __restrict__ S,   // [C-1][BF]
                     int B, int T, int F, int C1) {
    const int BF = B * F;
    int g = blockIdx.x * blockDim.x + threadIdx.x;
    if (g >= BF * C1) return;
    const int bf = g % BF;
    const int c  = g / BF;
    const int b  = bf / F;
    const int f  = bf - b * F;

    const float a   = sigmoidf_(alpha[f]);
    const float oma = 1.0f - a;

    const float* p = mag + ((size_t)b * T + (size_t)c * L) * F + f;

    // ---- deep prefetch: all L loads issued before the recurrence ----
    float m[L];
#pragma unroll
    for (int t = 0; t < L; ++t)
        m[t] = p[(size_t)t * F];
    asm volatile("" ::: "memory");   // pin loads: all L in flight

    float local = 0.0f;
#pragma unroll
    for (int t = 0; t < L; ++t)
        local = local * oma + (m[t] * m[t]) * a;  // exact reference form
    S[(size_t)c * BF + bf] = local;
}

template <int L>
__global__ __launch_bounds__(256)
void fns11_emit(const float* __restrict__ mag,
                const float* __restrict__ s0,
                const float* __restrict__ weights,
                const float* __restrict__ bias,
                const float* __restrict__ alpha,
                const float* __restrict__ S,   // [C-1][BF]
                float* __restrict__ out,
                int B, int T, int F, int C) {
    const int BF = B * F;
    int g = blockIdx.x * blockDim.x + threadIdx.x;
    if (g >= BF * C) return;
    const int bf = g % BF;
    const int c  = g / BF;
    const int b  = bf / F;
    const int f  = bf - b * F;

    const float a   = sigmoidf_(alpha[f]);
    const float oma = 1.0f - a;
    const float w   = weights[f];
    const float bi  = bias[f];

    // exact carry-in for chunk c (Horner over preceding chunk aggregates;
    // identical arithmetic to a sequential middle pass)
    float carry = s0[bf];
    if (c > 0) {
        float D = 1.0f;                      // (1-a)^L via product
#pragma unroll
        for (int i = 0; i < L; ++i) D *= oma;
        for (int j = 0; j < c; ++j)
            carry = carry * D + S[(size_t)j * BF + bf];
    }

    const float* p = mag + ((size_t)b * T + (size_t)c * L) * F + f;
    float*       o = out + ((size_t)b * T + (size_t)c * L) * F + f;

    // ---- deep prefetch: all L loads issued before any store ----
    float m[L];
#pragma unroll
    for (int t = 0; t < L; ++t)
        m[t] = p[(size_t)t * F];
    asm volatile("" ::: "memory");   // pin loads: all L in flight

#pragma unroll
    for (int t = 0; t < L; ++t) {
        carry = carry * oma + (m[t] * m[t]) * a;
        // 1/(sqrt+eps) via hw rcp (~1 ulp); bounded output -> abs err ~1e-6
        o[(size_t)t * F] = m[t] * __builtin_amdgcn_rcpf(sqrtf(carry) + EPS) * w + bi;
    }
}

// ---------------------------------------------------------------------------
// Fallback: one thread per (b,f) chain (general shapes / tiny workspace).
// ---------------------------------------------------------------------------
__global__ void fns_fallback(const float* __restrict__ mag,
                             const float* __restrict__ s0,
                             const float* __restrict__ weights,
                             const float* __restrict__ bias,
                             const float* __restrict__ alpha,
                             float* __restrict__ out,
                             int B, int T, int F) {
    int bf = blockIdx.x * blockDim.x + threadIdx.x;
    int BF = B * F;
    if (bf >= BF) return;
    int b = bf / F;
    int f = bf - b * F;

    float a  = sigmoidf_(alpha[f]);
    float w  = weights[f];
    float bi = bias[f];

    float carry = s0[bf];
    const float* p = mag + (size_t)b * T * F + f;
    float*       o = out + (size_t)b * T * F + f;

    for (int t = 0; t < T; ++t) {
        float m = p[(size_t)t * F];
        carry = carry * (1.0f - a) + (m * m) * a;
        o[(size_t)t * F] = m / (sqrtf(carry) + EPS) * w + bi;
    }
}

extern "C" void kernel_launch(void* const* d_in, const int* in_sizes, int n_in,
                              void* d_out, int out_size, void* d_ws, size_t ws_size,
                              hipStream_t stream) {
    const float* mag     = (const float*)d_in[0];
    const float* s0      = (const float*)d_in[1];
    const float* weights = (const float*)d_in[2];
    const float* bias    = (const float*)d_in[3];
    const float* alpha   = (const float*)d_in[4];
    float* out = (float*)d_out;

    int F  = in_sizes[4];          // alpha is [1, F]
    int BF = in_sizes[1];          // s is [B, F]
    int B  = BF / F;
    int T  = in_sizes[0] / BF;     // mag is [B, T, F]

    constexpr int L = 50;          // chunk length (compile-time, full unroll)
    if (T % L == 0) {
        int C  = T / L;            // 20 for T=1000
        int C1 = C - 1;
        size_t need = (size_t)C1 * BF * sizeof(float);
        if (C1 >= 1 && ws_size >= need) {
            float* S = (float*)d_ws;
            int n1 = BF * C1;                    // 312,512
            int n2 = BF * C;                     // 328,960
            fns11_aggregate<L><<<(n1 + 255) / 256, 256, 0, stream>>>(
                mag, alpha, S, B, T, F, C1);
            fns11_emit<L><<<(n2 + 255) / 256, 256, 0, stream>>>(
                mag, s0, weights, bias, alpha, S, out, B, T, F, C);
            return;
        }
    }

    int threads = 256;
    int blocks  = (BF + threads - 1) / threads;
    fns_fallback<<<blocks, threads, 0, stream>>>(mag, s0, weights, bias,
                                                 alpha, out, B, T, F);
}

// Round 12
// 42.565 us; speedup vs baseline: 1.0155x; 1.0155x over previous
//
#include <hip/hip_runtime.h>

#define EPS 1e-8f

__device__ __forceinline__ float sigmoidf_(float x) {
    return 1.0f / (1.0f + expf(-x));
}

// ---------------------------------------------------------------------------
// Two-kernel chunked scan (proven R10/R11 structure).
// NEW in R12: emit's Horner carry reconstruction prefetches ALL chunk
// aggregates into registers (masked, unrolled) instead of a dependent-load
// chain -- the loads fly in parallel, only the cheap VALU combine is serial.
// Load order in emit: mag m[L] first (HBM, long latency), then SS[C-1] (L2,
// short), then combine carry while mag is still in flight.
// ---------------------------------------------------------------------------

template <int L>
__global__ __launch_bounds__(256)
void fns12_aggregate(const float* __restrict__ mag,
                     const float* __restrict__ alpha,
                     float* __restrict__ S,   // [C-1][BF]
                     int B, int T, int F, int C1) {
    const int BF = B * F;
    int g = blockIdx.x * blockDim.x + threadIdx.x;
    if (g >= BF * C1) return;
    const int bf = g % BF;
    const int c  = g / BF;
    const int b  = bf / F;
    const int f  = bf - b * F;

    const float a   = sigmoidf_(alpha[f]);
    const float oma = 1.0f - a;

    const float* p = mag + ((size_t)b * T + (size_t)c * L) * F + f;

    // deep prefetch: all L loads issued before the recurrence
    float m[L];
#pragma unroll
    for (int t = 0; t < L; ++t)
        m[t] = p[(size_t)t * F];
    asm volatile("" ::: "memory");

    float local = 0.0f;
#pragma unroll
    for (int t = 0; t < L; ++t)
        local = local * oma + (m[t] * m[t]) * a;  // exact reference form
    S[(size_t)c * BF + bf] = local;
}

template <int L, int C>
__global__ __launch_bounds__(256)
void fns12_emit(const float* __restrict__ mag,
                const float* __restrict__ s0,
                const float* __restrict__ weights,
                const float* __restrict__ bias,
                const float* __restrict__ alpha,
                const float* __restrict__ S,   // [C-1][BF]
                float* __restrict__ out,
                int B, int T, int F) {
    const int BF = B * F;
    int g = blockIdx.x * blockDim.x + threadIdx.x;
    if (g >= BF * C) return;
    const int bf = g % BF;
    const int c  = g / BF;
    const int b  = bf / F;
    const int f  = bf - b * F;

    const float a   = sigmoidf_(alpha[f]);
    const float oma = 1.0f - a;
    const float w   = weights[f];
    const float bi  = bias[f];

    const float* p = mag + ((size_t)b * T + (size_t)c * L) * F + f;
    float*       o = out + ((size_t)b * T + (size_t)c * L) * F + f;

    // ---- deep prefetch 1: mag (HBM, longest latency) ----
    float m[L];
#pragma unroll
    for (int t = 0; t < L; ++t)
        m[t] = p[(size_t)t * F];

    // ---- deep prefetch 2: chunk aggregates (L2-resident), masked ----
    float SS[C - 1];
#pragma unroll
    for (int j = 0; j < C - 1; ++j)
        SS[j] = (j < c) ? S[(size_t)j * BF + bf] : 0.0f;
    asm volatile("" ::: "memory");   // pin all loads before first use

    // ---- carry combine: pure VALU, identical arithmetic to sequential pass
    float D = 1.0f;                  // (1-a)^L via product
#pragma unroll
    for (int i = 0; i < L; ++i) D *= oma;
    float carry = s0[bf];
#pragma unroll
    for (int j = 0; j < C - 1; ++j)
        carry = (j < c) ? (carry * D + SS[j]) : carry;

    // ---- scan + normalize + store ----
#pragma unroll
    for (int t = 0; t < L; ++t) {
        carry = carry * oma + (m[t] * m[t]) * a;
        // 1/(sqrt+eps) via hw rcp (~1 ulp); bounded output -> abs err ~1e-6
        o[(size_t)t * F] = m[t] * __builtin_amdgcn_rcpf(sqrtf(carry) + EPS) * w + bi;
    }
}

// Generic emit (runtime C) -- proven R11 form, for non-standard shapes.
template <int L>
__global__ __launch_bounds__(256)
void fns11_emit(const float* __restrict__ mag,
                const float* __restrict__ s0,
                const float* __restrict__ weights,
                const float* __restrict__ bias,
                const float* __restrict__ alpha,
                const float* __restrict__ S,
                float* __restrict__ out,
                int B, int T, int F, int C) {
    const int BF = B * F;
    int g = blockIdx.x * blockDim.x + threadIdx.x;
    if (g >= BF * C) return;
    const int bf = g % BF;
    const int c  = g / BF;
    const int b  = bf / F;
    const int f  = bf - b * F;

    const float a   = sigmoidf_(alpha[f]);
    const float oma = 1.0f - a;
    const float w   = weights[f];
    const float bi  = bias[f];

    float carry = s0[bf];
    if (c > 0) {
        float D = 1.0f;
#pragma unroll
        for (int i = 0; i < L; ++i) D *= oma;
        for (int j = 0; j < c; ++j)
            carry = carry * D + S[(size_t)j * BF + bf];
    }

    const float* p = mag + ((size_t)b * T + (size_t)c * L) * F + f;
    float*       o = out + ((size_t)b * T + (size_t)c * L) * F + f;

    float m[L];
#pragma unroll
    for (int t = 0; t < L; ++t)
        m[t] = p[(size_t)t * F];
    asm volatile("" ::: "memory");

#pragma unroll
    for (int t = 0; t < L; ++t) {
        carry = carry * oma + (m[t] * m[t]) * a;
        o[(size_t)t * F] = m[t] * __builtin_amdgcn_rcpf(sqrtf(carry) + EPS) * w + bi;
    }
}

__global__ void fns_fallback(const float* __restrict__ mag,
                             const float* __restrict__ s0,
                             const float* __restrict__ weights,
                             const float* __restrict__ bias,
                             const float* __restrict__ alpha,
                             float* __restrict__ out,
                             int B, int T, int F) {
    int bf = blockIdx.x * blockDim.x + threadIdx.x;
    int BF = B * F;
    if (bf >= BF) return;
    int b = bf / F;
    int f = bf - b * F;

    float a  = sigmoidf_(alpha[f]);
    float w  = weights[f];
    float bi = bias[f];

    float carry = s0[bf];
    const float* p = mag + (size_t)b * T * F + f;
    float*       o = out + (size_t)b * T * F + f;

    for (int t = 0; t < T; ++t) {
        float m = p[(size_t)t * F];
        carry = carry * (1.0f - a) + (m * m) * a;
        o[(size_t)t * F] = m / (sqrtf(carry) + EPS) * w + bi;
    }
}

extern "C" void kernel_launch(void* const* d_in, const int* in_sizes, int n_in,
                              void* d_out, int out_size, void* d_ws, size_t ws_size,
                              hipStream_t stream) {
    const float* mag     = (const float*)d_in[0];
    const float* s0      = (const float*)d_in[1];
    const float* weights = (const float*)d_in[2];
    const float* bias    = (const float*)d_in[3];
    const float* alpha   = (const float*)d_in[4];
    float* out = (float*)d_out;

    int F  = in_sizes[4];          // alpha is [1, F]
    int BF = in_sizes[1];          // s is [B, F]
    int B  = BF / F;
    int T  = in_sizes[0] / BF;     // mag is [B, T, F]

    constexpr int L = 50;          // chunk length (compile-time, full unroll)
    if (T % L == 0) {
        int C  = T / L;            // 20 for T=1000
        int C1 = C - 1;
        size_t need = (size_t)C1 * BF * sizeof(float);
        if (C1 >= 1 && ws_size >= need) {
            float* S = (float*)d_ws;
            int n1 = BF * C1;                    // 312,512
            int n2 = BF * C;                     // 328,960
            fns12_aggregate<L><<<(n1 + 255) / 256, 256, 0, stream>>>(
                mag, alpha, S, B, T, F, C1);
            if (C == 20) {
                fns12_emit<L, 20><<<(n2 + 255) / 256, 256, 0, stream>>>(
                    mag, s0, weights, bias, alpha, S, out, B, T, F);
            } else {
                fns11_emit<L><<<(n2 + 255) / 256, 256, 0, stream>>>(
                    mag, s0, weights, bias, alpha, S, out, B, T, F, C);
            }
            return;
        }
    }

    int threads = 256;
    int blocks  = (BF + threads - 1) / threads;
    fns_fallback<<<blocks, threads, 0, stream>>>(mag, s0, weights, bias,
                                                 alpha, out, B, T, F);
}